// Round 11
// baseline (259.102 us; speedup 1.0000x reference)
//
#include <hip/hip_runtime.h>

// StochasticRegionalConvolution — fused MFMA conv, A-frags in LDS.
// out[b,co,p,q] = coeff(p,q) * sum_{ci,kh,kw} x[b,ci,p+kh,q+kw] * W[co,ci,kh,kw]
//
// K1: coeff map (256x256 f32)                     -> d_ws[0, 256KB)
// K2: weight transform to MFMA A-frag order, bf16 -> d_ws[256KB, 328KB)
// K3: fused conv: 16x32 pixel tile, 512 thr / 8 waves, two ci-half passes.
//     Per half: x patch -> LDS xs[612][16 u32] (swizzled), A-frags (36KB)
//     -> LDS af_lds. Compute loop is pure ds_read_b128 + MFMA (no global).
//     LDS 76KB -> 2 blocks/CU. Barrier-free per-wave epilogue, full-line
//     float4 stores. Bijective XCD swizzle.

typedef short short8 __attribute__((ext_vector_type(8)));
typedef float floatx4 __attribute__((ext_vector_type(4)));
typedef unsigned int uint4v __attribute__((ext_vector_type(4)));

#define OUTR 62

__device__ inline unsigned f2bf_pack(float lo, float hi) {
    unsigned ul = __builtin_bit_cast(unsigned, lo);
    unsigned uh = __builtin_bit_cast(unsigned, hi);
    ul = (ul + 0x7FFFu + ((ul >> 16) & 1u)) >> 16;   // RNE
    uh = (uh + 0x7FFFu + ((uh >> 16) & 1u)) >> 16;
    return ul | (uh << 16);
}

__global__ void srconv_coeff_kernel(const int* __restrict__ h_idx,
                                    const int* __restrict__ w_idx,
                                    const float* __restrict__ lam,
                                    int T, float* __restrict__ coeff) {
    int p = blockIdx.x;
    int q = threadIdx.x;
    float c = 0.f;
    for (int t = 0; t < T; ++t) {
        int dh = p - h_idx[t];
        int dw = q - w_idx[t];
        if (dh >= 0 && dh < OUTR && dw >= 0 && dw < OUTR) c += lam[t];
    }
    coeff[(p << 8) + q] = c * (1.0f / 16.0f);
}

__global__ void srconv_wtrans_kernel(const float* __restrict__ wgt,
                                     uint4v* __restrict__ afrag) {
    int id = blockIdx.x * 256 + threadIdx.x;      // [0, 72*64)
    int l  = id & 63;
    int fi = id >> 6;                             // (kk*2+cb)*4 + m
    int m  = fi & 3;
    int cb = (fi >> 2) & 1;
    int kk = fi >> 3;
    int co  = m * 16 + (l & 15);
    int ci0 = cb * 32 + (l >> 4) * 8;
    float w[8];
#pragma unroll
    for (int j = 0; j < 8; ++j)
        w[j] = wgt[(co * 64 + ci0 + j) * 9 + kk];
    uint4v d;
    d.x = f2bf_pack(w[0], w[1]);
    d.y = f2bf_pack(w[2], w[3]);
    d.z = f2bf_pack(w[4], w[5]);
    d.w = f2bf_pack(w[6], w[7]);
    afrag[id] = d;
}

// LDS xs[pix 0..611][16 u32 ci-pairs], slot = cp ^ (((pix>>1)&3)<<2).
// B-frag (kg): b128 at slot16 = (kg ^ ((pix>>1)&3))*4 -> ci 8kg..8kg+7 in order.
// af_lds[e]: e = kk*256 + m*64 + lane (uint4v units), linear conflict-free.
__launch_bounds__(512, 4)
__global__ void srconv_fused_kernel(const float* __restrict__ x,
                                    const float* __restrict__ coeff,
                                    const uint4v* __restrict__ afrag,
                                    float* __restrict__ out) {
    __shared__ __align__(16) unsigned xs[612 * 16];   // 39,168 B
    __shared__ uint4v af_lds[2304];                   // 36,864 B

    const int tid  = threadIdx.x;
    const int lane = tid & 63;
    const int wv   = tid >> 6;            // 0..7 -> p-rows {2wv, 2wv+1}
    const int l15  = lane & 15;
    const int kg   = lane >> 4;

    // bijective XCD swizzle: 2048 blocks, 8 XCDs x 256 -> 2 batches per XCD
    const unsigned bid = blockIdx.x;
    const unsigned swz = (bid & 7) * 256 + (bid >> 3);
    const int b    = swz >> 7;
    const int tile = swz & 127;           // 16 p-tiles x 8 q-tiles
    const int P0   = (tile >> 3) << 4;
    const int Q0   = (tile & 7) << 5;

    // ---- tile skip vote ----
    float myc = coeff[((P0 + (tid >> 5)) << 8) + Q0 + (tid & 31)];
    if (__syncthreads_count(myc != 0.f) == 0) {
        const floatx4 z = (floatx4){0.f, 0.f, 0.f, 0.f};
        for (int u = tid; u < 64 * 16 * 8; u += 512) {
            int q4 = u & 7;
            int pr = (u >> 3) & 15;
            int co = u >> 7;
            *(floatx4*)(out + (((b << 6) + co) << 16) +
                        ((P0 + pr) << 8) + Q0 + (q4 << 2)) = z;
        }
        return;
    }

    floatx4 acc[4][2][2];                 // [m: co16][p: row][h: q-half]
#pragma unroll
    for (int m = 0; m < 4; ++m)
#pragma unroll
        for (int p = 0; p < 2; ++p)
#pragma unroll
            for (int h = 0; h < 2; ++h)
                acc[m][p][h] = (floatx4){0.f, 0.f, 0.f, 0.f};

    const float* xb  = x + ((size_t)b << 22);
    const int    prb = P0 + (wv << 1);

    for (int cb = 0; cb < 2; ++cb) {
        if (cb) __syncthreads();          // WAR: half0 reads done before restage
        // ---- stage x half: 2592 tasks = 16 ci-pairs x 18 rows x 9 chunks
#pragma unroll
        for (int r = 0; r < 6; ++r) {
            int u  = r * 512 + tid;
            int uc = u < 2592 ? u : 2591;
            int cp    = uc / 162;
            int rem   = uc - cp * 162;
            int row   = rem / 9;
            int chunk = rem - row * 9;
            int gr    = min(P0 + row, 255);
            int gcb   = min(Q0 + (chunk << 2), 252);
            const float* xp = xb + (((cb << 4) + cp) << 17) + (gr << 8) + gcb;
            const floatx4 v0 = *(const floatx4*)(xp);
            const floatx4 v1 = *(const floatx4*)(xp + 65536);
            const int c4 = chunk << 2;
#pragma unroll
            for (int j = 0; j < 4; ++j) {
                if (u < 2592 && c4 + j < 34) {
                    int pix = row * 34 + c4 + j;
                    int slot = cp ^ (((pix >> 1) & 3) << 2);
                    xs[(pix << 4) + slot] = f2bf_pack(v0[j], v1[j]);
                }
            }
        }
        // ---- stage A half: 2304 uint4v, linear ----
#pragma unroll
        for (int i = 0; i < 5; ++i) {
            int e = i * 512 + tid;
            if (e < 2304)
                af_lds[e] = afrag[((e >> 8) << 9) + (cb << 8) + (e & 255)];
        }
        __syncthreads();

        // ---- compute: 9 taps, pure LDS + MFMA ----
#pragma unroll
        for (int kk = 0; kk < 9; ++kk) {
            const int kh = kk / 3;
            const int kw = kk - kh * 3;
            short8 a[4];
#pragma unroll
            for (int m = 0; m < 4; ++m)
                a[m] = *reinterpret_cast<const short8*>(
                    &af_lds[(kk << 8) + (m << 6) + lane]);
            short8 bf[2][2];
#pragma unroll
            for (int p = 0; p < 2; ++p)
#pragma unroll
                for (int h = 0; h < 2; ++h) {
                    int prl = (wv << 1) + p + kh;          // 0..17
                    int cl  = (h << 4) + l15 + kw;         // 0..33
                    int pix = prl * 34 + cl;
                    int off = (pix << 4) +
                              ((kg << 2) ^ (((pix >> 1) & 3) << 2));
                    bf[p][h] = *(const short8*)(&xs[off]);
                }
#pragma unroll
            for (int m = 0; m < 4; ++m)
#pragma unroll
                for (int p = 0; p < 2; ++p)
#pragma unroll
                    for (int h = 0; h < 2; ++h)
                        acc[m][p][h] = __builtin_amdgcn_mfma_f32_16x16x32_bf16(
                            a[m], bf[p][h], acc[m][p][h], 0, 0, 0);
        }
    }
    __syncthreads();                      // all waves done reading xs

    // ---- epilogue: per-wave ping-pong slabs overlaid on xs, no barriers
    // D layout (m89): col = lane&15 -> q, row = (lane>>4)*4+reg -> co-within-16
    float cf[2][2];
#pragma unroll
    for (int p = 0; p < 2; ++p)
#pragma unroll
        for (int h = 0; h < 2; ++h)
            cf[p][h] = coeff[((prb + p) << 8) + Q0 + (h << 4) + l15];

    float* epb = reinterpret_cast<float*>(xs);
    const int co_l = lane >> 3;           // 0..7
    const int q4   = lane & 7;

#pragma unroll
    for (int p = 0; p < 2; ++p) {
        const int pr = prb + p;
#pragma unroll
        for (int m = 0; m < 4; ++m) {
            float* ep = epb + (((wv << 1) + (m & 1)) * 576);
#pragma unroll
            for (int h = 0; h < 2; ++h)
#pragma unroll
                for (int reg = 0; reg < 4; ++reg)
                    ep[((kg << 2) + reg) * 36 + (h << 4) + l15] =
                        acc[m][p][h][reg] * cf[p][h];
            // wave-internal RAW through LDS: compiler-inserted lgkmcnt orders
#pragma unroll
            for (int j = 0; j < 2; ++j) {
                const floatx4 v = *reinterpret_cast<const floatx4*>(
                    &ep[(co_l + (j << 3)) * 36 + (q4 << 2)]);
                const int co = (m << 4) + co_l + (j << 3);
                *(floatx4*)(out + (((b << 6) + co) << 16) +
                            (pr << 8) + Q0 + (q4 << 2)) = v;
            }
        }
    }
}

extern "C" void kernel_launch(void* const* d_in, const int* in_sizes, int n_in,
                              void* d_out, int out_size, void* d_ws, size_t ws_size,
                              hipStream_t stream) {
    const float* x     = (const float*)d_in[0];
    const float* wgt   = (const float*)d_in[1];
    const int*   h_idx = (const int*)d_in[2];
    const int*   w_idx = (const int*)d_in[3];
    const float* lam   = (const float*)d_in[4];
    float*       out   = (float*)d_out;
    float*       coeff = (float*)d_ws;                        // 256 KB
    char*        af_b  = (char*)d_ws + 65536 * sizeof(float); // 72 KB
    const int    T     = in_sizes[2];

    srconv_coeff_kernel<<<256, 256, 0, stream>>>(h_idx, w_idx, lam, T, coeff);
    srconv_wtrans_kernel<<<18, 256, 0, stream>>>(wgt, (uint4v*)af_b);
    // 2048 blocks = (16 p-tiles x 8 q-tiles) x 16 batches, XCD-swizzled
    srconv_fused_kernel<<<2048, 512, 0, stream>>>(
        x, coeff, (const uint4v*)af_b, out);
}

// Round 12
// 191.911 us; speedup vs baseline: 1.3501x; 1.3501x over previous
//
#include <hip/hip_runtime.h>

// StochasticRegionalConvolution — fused MFMA conv, upfront dbuf staging.
// out[b,co,p,q] = coeff(p,q) * sum_{ci,kh,kw} x[b,ci,p+kh,q+kw] * W[co,ci,kh,kw]
//
// K1: coeff map (256x256 f32)                     -> d_ws[0, 256KB)
// K2: weight transform to MFMA A-frag order, bf16 -> d_ws[256KB, 328KB)
// K3: fused conv: 8x32 pixel tile, 256 thr / 4 waves, launch_bounds(256,3).
//     BOTH ci-halves staged upfront into xs[2][340][16] (43.5KB, one barrier);
//     18 K-phases fully unrolled with a continuous 2-slot afrag prefetch
//     pipeline (no cb-boundary bubble). Barrier-free per-wave epilogue with
//     full-128B-line float4 stores. Bijective XCD swizzle.

typedef short short8 __attribute__((ext_vector_type(8)));
typedef float floatx4 __attribute__((ext_vector_type(4)));
typedef unsigned int uint4v __attribute__((ext_vector_type(4)));

#define OUTR 62

__device__ inline unsigned f2bf_pack(float lo, float hi) {
    unsigned ul = __builtin_bit_cast(unsigned, lo);
    unsigned uh = __builtin_bit_cast(unsigned, hi);
    ul = (ul + 0x7FFFu + ((ul >> 16) & 1u)) >> 16;   // RNE
    uh = (uh + 0x7FFFu + ((uh >> 16) & 1u)) >> 16;
    return ul | (uh << 16);
}

__global__ void srconv_coeff_kernel(const int* __restrict__ h_idx,
                                    const int* __restrict__ w_idx,
                                    const float* __restrict__ lam,
                                    int T, float* __restrict__ coeff) {
    int p = blockIdx.x;
    int q = threadIdx.x;
    float c = 0.f;
    for (int t = 0; t < T; ++t) {
        int dh = p - h_idx[t];
        int dw = q - w_idx[t];
        if (dh >= 0 && dh < OUTR && dw >= 0 && dw < OUTR) c += lam[t];
    }
    coeff[(p << 8) + q] = c * (1.0f / 16.0f);
}

__global__ void srconv_wtrans_kernel(const float* __restrict__ wgt,
                                     uint4v* __restrict__ afrag) {
    int id = blockIdx.x * 256 + threadIdx.x;      // [0, 72*64)
    int l  = id & 63;
    int fi = id >> 6;                             // (kk*2+cb)*4 + m
    int m  = fi & 3;
    int cb = (fi >> 2) & 1;
    int kk = fi >> 3;
    int co  = m * 16 + (l & 15);
    int ci0 = cb * 32 + (l >> 4) * 8;
    float w[8];
#pragma unroll
    for (int j = 0; j < 8; ++j)
        w[j] = wgt[(co * 64 + ci0 + j) * 9 + kk];
    uint4v d;
    d.x = f2bf_pack(w[0], w[1]);
    d.y = f2bf_pack(w[2], w[3]);
    d.z = f2bf_pack(w[4], w[5]);
    d.w = f2bf_pack(w[6], w[7]);
    afrag[id] = d;
}

// LDS xs[cb][pix 0..339][16 u32 ci-pairs], slot = cpl ^ (((pix>>1)&3)<<2).
// B-frag (kg): b128 at slot16 = kg ^ ((pix>>1)&3) -> ci 8kg..8kg+7 in order.
__launch_bounds__(256, 3)
__global__ void srconv_fused_kernel(const float* __restrict__ x,
                                    const float* __restrict__ coeff,
                                    const short8* __restrict__ afrag,
                                    float* __restrict__ out) {
    __shared__ __align__(16) unsigned xs[2 * 340 * 16];   // 43,520 B

    const int tid  = threadIdx.x;
    const int lane = tid & 63;
    const int wv   = tid >> 6;            // 0..3 -> p-rows {2wv, 2wv+1}
    const int l15  = lane & 15;
    const int kg   = lane >> 4;

    // bijective XCD swizzle: 4096 blocks, 8 XCDs x 512 -> 2 batches per XCD
    const unsigned bid = blockIdx.x;
    const unsigned swz = (bid & 7) * 512 + (bid >> 3);
    const int b    = swz >> 8;
    const int tile = swz & 255;           // 32 p-tiles x 8 q-tiles
    const int P0   = (tile >> 3) << 3;
    const int Q0   = (tile & 7) << 5;

    // ---- tile skip vote: 256 threads cover the 8x32 coeff tile ----
    float myc = coeff[((P0 + (tid >> 5)) << 8) + Q0 + (tid & 31)];
    if (__syncthreads_count(myc != 0.f) == 0) {
        const floatx4 z = (floatx4){0.f, 0.f, 0.f, 0.f};
        for (int u = tid; u < 64 * 8 * 8; u += 256) {
            int q4 = u & 7;
            int pr = (u >> 3) & 7;
            int co = u >> 6;
            *(floatx4*)(out + (((b << 6) + co) << 16) +
                        ((P0 + pr) << 8) + Q0 + (q4 << 2)) = z;
        }
        return;
    }

    const int prb = P0 + (wv << 1);

    // ---- hoisted epilogue coeff loads (L2-hot, issue early) ----
    float cf[2][2];
#pragma unroll
    for (int p = 0; p < 2; ++p)
#pragma unroll
        for (int h = 0; h < 2; ++h)
            cf[p][h] = coeff[((prb + p) << 8) + Q0 + (h << 4) + l15];

    const float* xb = x + ((size_t)b << 22);

    // ---- stage BOTH ci-halves upfront: 2880 tasks = 32 cp x 10 rows x 9 chunks
    // task: 2 float4 loads (4 px, ci 2cp/2cp+1) -> 4 packed u32 -> 4 b32 writes
#pragma unroll
    for (int r = 0; r < 12; ++r) {
        int u  = r * 256 + tid;
        int uc = u < 2880 ? u : 2879;
        int cp    = uc / 90;              // 0..31 (all 64 ci as pairs)
        int rem   = uc - cp * 90;
        int row   = rem / 9;
        int chunk = rem - row * 9;
        int gr    = min(P0 + row, 255);
        int gcb   = min(Q0 + (chunk << 2), 252);
        const float* xp = xb + (cp << 17) + (gr << 8) + gcb;
        const floatx4 v0 = *(const floatx4*)(xp);
        const floatx4 v1 = *(const floatx4*)(xp + 65536);
        const int c4  = chunk << 2;
        const int cbo = (cp >> 4) * 5440; // half select
        const int cpl = cp & 15;
#pragma unroll
        for (int j = 0; j < 4; ++j) {
            if (u < 2880 && c4 + j < 34) {
                int pix = row * 34 + c4 + j;
                int slot = cpl ^ (((pix >> 1) & 3) << 2);
                xs[cbo + (pix << 4) + slot] = f2bf_pack(v0[j], v1[j]);
            }
        }
    }
    __syncthreads();

    // ---- compute: 18 phases (t = cb*9 + kk), continuous 2-slot A pipeline ----
    floatx4 acc[4][2][2];                 // [m: co16][p: row][h: q-half]
#pragma unroll
    for (int m = 0; m < 4; ++m)
#pragma unroll
        for (int p = 0; p < 2; ++p)
#pragma unroll
            for (int h = 0; h < 2; ++h)
                acc[m][p][h] = (floatx4){0.f, 0.f, 0.f, 0.f};

    short8 areg[2][4];
    // preload phases 0 and 1:  frag idx fi(t,m) = ((t%9)*2 + t/9)*4 + m
#pragma unroll
    for (int m = 0; m < 4; ++m) {
        areg[0][m] = afrag[((0 * 2 + 0) * 4 + m) * 64 + lane];   // t=0: kk0,cb0
        areg[1][m] = afrag[((1 * 2 + 0) * 4 + m) * 64 + lane];   // t=1: kk1,cb0
    }

#pragma unroll
    for (int t = 0; t < 18; ++t) {
        const int cb = t / 9;
        const int kk = t - cb * 9;
        const int kh = kk / 3;
        const int kw = kk - kh * 3;
        const int cur = t & 1;

        short8 bf[2][2];
#pragma unroll
        for (int p = 0; p < 2; ++p)
#pragma unroll
            for (int h = 0; h < 2; ++h) {
                int prl = (wv << 1) + p + kh;          // 0..9
                int cl  = (h << 4) + l15 + kw;         // 0..33
                int pix = prl * 34 + cl;
                int off = cb * 5440 + (pix << 4) +
                          ((kg << 2) ^ (((pix >> 1) & 3) << 2));
                bf[p][h] = *(const short8*)(&xs[off]);
            }
#pragma unroll
        for (int m = 0; m < 4; ++m)
#pragma unroll
            for (int p = 0; p < 2; ++p)
#pragma unroll
                for (int h = 0; h < 2; ++h)
                    acc[m][p][h] = __builtin_amdgcn_mfma_f32_16x16x32_bf16(
                        areg[cur][m], bf[p][h], acc[m][p][h], 0, 0, 0);

        // prefetch phase t+2 into the slot just consumed
        if (t < 16) {
            const int tn  = t + 2;
            const int cbn = tn / 9;
            const int kkn = tn - cbn * 9;
#pragma unroll
            for (int m = 0; m < 4; ++m)
                areg[cur][m] =
                    afrag[(((kkn << 1) + cbn) * 4 + m) * 64 + lane];
        }
    }
    __syncthreads();                      // all waves done reading xs

    // ---- epilogue: per-wave ping-pong slabs overlaid on xs, no barriers
    // D layout (m89): col = lane&15 -> q, row = (lane>>4)*4+reg -> co-within-16
    float* epb = reinterpret_cast<float*>(xs);
    const int co_l = lane >> 3;           // 0..7
    const int q4   = lane & 7;

#pragma unroll
    for (int p = 0; p < 2; ++p) {
        const int pr = prb + p;
#pragma unroll
        for (int m = 0; m < 4; ++m) {
            float* ep = epb + (((wv << 1) + (m & 1)) * 576);
#pragma unroll
            for (int h = 0; h < 2; ++h)
#pragma unroll
                for (int reg = 0; reg < 4; ++reg)
                    ep[((kg << 2) + reg) * 36 + (h << 4) + l15] =
                        acc[m][p][h][reg] * cf[p][h];
            // wave-internal RAW through LDS: compiler-inserted lgkmcnt orders
#pragma unroll
            for (int j = 0; j < 2; ++j) {
                const floatx4 v = *reinterpret_cast<const floatx4*>(
                    &ep[(co_l + (j << 3)) * 36 + (q4 << 2)]);
                const int co = (m << 4) + co_l + (j << 3);
                *(floatx4*)(out + (((b << 6) + co) << 16) +
                            (pr << 8) + Q0 + (q4 << 2)) = v;
            }
        }
    }
}

extern "C" void kernel_launch(void* const* d_in, const int* in_sizes, int n_in,
                              void* d_out, int out_size, void* d_ws, size_t ws_size,
                              hipStream_t stream) {
    const float* x     = (const float*)d_in[0];
    const float* wgt   = (const float*)d_in[1];
    const int*   h_idx = (const int*)d_in[2];
    const int*   w_idx = (const int*)d_in[3];
    const float* lam   = (const float*)d_in[4];
    float*       out   = (float*)d_out;
    float*       coeff = (float*)d_ws;                        // 256 KB
    char*        af_b  = (char*)d_ws + 65536 * sizeof(float); // 72 KB
    const int    T     = in_sizes[2];

    srconv_coeff_kernel<<<256, 256, 0, stream>>>(h_idx, w_idx, lam, T, coeff);
    srconv_wtrans_kernel<<<18, 256, 0, stream>>>(wgt, (uint4v*)af_b);
    // 4096 blocks = (32 p-tiles x 8 q-tiles) x 16 batches, XCD-swizzled
    srconv_fused_kernel<<<4096, 256, 0, stream>>>(
        x, coeff, (const short8*)af_b, out);
}